// Round 4
// baseline (1628.957 us; speedup 1.0000x reference)
//
#include <hip/hip_runtime.h>

#define Bn 128
#define Wn 64

typedef _Float16 h2 __attribute__((ext_vector_type(2)));

// ---- inter-WG exchange state (flags reset every launch) ----
__device__ unsigned g_f1[256];               // score-partial ready, value = t+1
__device__ unsigned g_f2[256];               // state-half ready, value = t+1
__device__ unsigned g_att[256][64];          // score partials (f32 bits)
__device__ unsigned g_state[256][128];       // h pairs [0..64), c pairs [64..128)
__device__ unsigned g_ep16[Bn * Wn * 128];   // eproj f16 pairs [b][w][128]
__device__ float4 g_encfc[Bn * Wn];          // fc_w[:, :256] @ enc  per (b,w)
__device__ float4 g_encfcf[Bn * Wn];         // fcf_w[:, 256:] @ enc per (b,w)

__device__ __forceinline__ float ftanh(float x) {
  float p = __builtin_exp2f(x * 2.885390081777927f);
  return 1.0f - 2.0f * __builtin_amdgcn_rcpf(p + 1.0f);
}
__device__ __forceinline__ float fsigm(float x) {
  float p = __builtin_exp2f(-x * 1.4426950408889634f);
  return __builtin_amdgcn_rcpf(1.0f + p);
}
__device__ __forceinline__ float dot4(float4 a, float4 b) {
  return a.x * b.x + a.y * b.y + a.z * b.z + a.w * b.w;
}
__device__ __forceinline__ float fd2(unsigned w, unsigned h, float acc) {
  h2 a = __builtin_bit_cast(h2, w), b = __builtin_bit_cast(h2, h);
#if __has_builtin(__builtin_amdgcn_fdot2)
  return __builtin_amdgcn_fdot2(a, b, acc, false);
#else
  return acc + (float)a.x * (float)b.x + (float)a.y * (float)b.y;
#endif
}
__device__ __forceinline__ float fd2x4u(uint4 w, uint4 h, float acc) {
  acc = fd2(w.x, h.x, acc);
  acc = fd2(w.y, h.y, acc);
  acc = fd2(w.z, h.z, acc);
  acc = fd2(w.w, h.w, acc);
  return acc;
}
__device__ __forceinline__ unsigned pk(float a, float b) {
  h2 h = {(_Float16)a, (_Float16)b};
  return __builtin_bit_cast(unsigned, h);
}
__device__ __forceinline__ void ast(unsigned* p, unsigned v) {
  __hip_atomic_store(p, v, __ATOMIC_RELAXED, __HIP_MEMORY_SCOPE_AGENT);
}
__device__ __forceinline__ void ast_rel(unsigned* p, unsigned v) {
  __hip_atomic_store(p, v, __ATOMIC_RELEASE, __HIP_MEMORY_SCOPE_AGENT);
}
__device__ __forceinline__ unsigned ald(unsigned* p) {
  return __hip_atomic_load(p, __ATOMIC_RELAXED, __HIP_MEMORY_SCOPE_AGENT);
}
__device__ __forceinline__ unsigned ald_acq(unsigned* p) {
  return __hip_atomic_load(p, __ATOMIC_ACQUIRE, __HIP_MEMORY_SCOPE_AGENT);
}

// ---------------- reset: flags + out (atomicAdd target) ----------------
__global__ void reset_kernel(float* out) {
  int t = threadIdx.x;
  if (t < 256) { g_f1[t] = 0u; g_f2[t] = 0u; }
  if (t < 512) out[t] = 0.f;
}

// ---------------- eproj: b1 + W1e @ enc -> f16 pairs ----------------
__global__ __launch_bounds__(256) void eproj_kernel(const float* __restrict__ enc,
                                                    const float* __restrict__ w1,
                                                    const float* __restrict__ b1) {
  __shared__ __align__(16) float4 encs[16][64];
  __shared__ float accs[16][256];
  const int m0 = blockIdx.x * 16;
  const int tid = threadIdx.x;
  const float4* eg = (const float4*)(enc + (size_t)m0 * 256);
#pragma unroll
  for (int i = 0; i < 4; i++) {
    int idx = tid + 256 * i;
    encs[idx >> 6][idx & 63] = eg[idx];
  }
  __syncthreads();
  const int e = tid;
  float acc[16];
#pragma unroll
  for (int i = 0; i < 16; i++) acc[i] = 0.f;
  const float4* wrow = (const float4*)(w1 + e * 768 + 512);
  for (int k4 = 0; k4 < 64; k4++) {
    float4 wv = wrow[k4];
#pragma unroll
    for (int i = 0; i < 16; i++) acc[i] += dot4(wv, encs[i][k4]);
  }
  float bb = b1[e];
#pragma unroll
  for (int i = 0; i < 16; i++) accs[i][e] = acc[i] + bb;
  __syncthreads();
#pragma unroll
  for (int r = 0; r < 8; r++) {
    int idx = r * 256 + tid;  // 0..2047
    int i = idx >> 7, jp = idx & 127;
    g_ep16[(size_t)(m0 + i) * 128 + jp] = pk(accs[i][2 * jp], accs[i][2 * jp + 1]);
  }
}

// ---------------- ENCFC / ENCFCF precompute ----------------
__global__ __launch_bounds__(256) void encfc_kernel(const float* __restrict__ enc,
                                                    const float* __restrict__ fc_w,
                                                    const float* __restrict__ fcf_w) {
  __shared__ __align__(16) float4 encs[16][64];
  const int m0 = blockIdx.x * 16;
  const int tid = threadIdx.x;
  const float4* eg = (const float4*)(enc + (size_t)m0 * 256);
#pragma unroll
  for (int i = 0; i < 4; i++) {
    int idx = tid + 256 * i;
    encs[idx >> 6][idx & 63] = eg[idx];
  }
  __syncthreads();
  if (tid < 128) {
    const int r = tid >> 3, o = tid & 7;
    const float* wr = (o < 4) ? (fc_w + o * 260) : (fcf_w + (o - 4) * 512 + 256);
    const float4* w4 = (const float4*)wr;
    float a = 0.f;
#pragma unroll 8
    for (int k = 0; k < 64; k++) a += dot4(w4[k], encs[r][k]);
    if (o < 4) ((float*)&g_encfc[m0 + r])[o] = a;
    else ((float*)&g_encfcf[m0 + r])[o - 4] = a;
  }
}

// ---------------- decoder: WG pair per chain; weights truly register-resident ----------------
__global__ __launch_bounds__(256, 1) void decoder_kernel(
    const float* __restrict__ w1, const float* __restrict__ w_hh,
    const float* __restrict__ yhist, const float* __restrict__ w2,
    const float* __restrict__ w_ih, const float* __restrict__ b_ih,
    const float* __restrict__ b_hh,
    const float* __restrict__ fc_w, const float* __restrict__ fc_b,
    const float* __restrict__ fcf_w, const float* __restrict__ fcf_b,
    float* __restrict__ out) {
  __shared__ unsigned ep16[64 * 68 + 8];  // own e-half pairs, stride 68 words
  __shared__ unsigned st_l[256];          // h pairs [0..128), c pairs [128..256)
  __shared__ float hcp_l[256];            // only own half used
  __shared__ float att_l[64];
  __shared__ __align__(16) float4 encfc_l[64];
  __shared__ __align__(16) float4 encfcf_l[64];
  __shared__ float w2_l[128];
  __shared__ float fcy_l[16];
  __shared__ float fcb_l[4];
  __shared__ float ai_l[128], ag_l[128], af_l[128], ao_l[128];
  __shared__ float hn_l[128];
  __shared__ float c32_l[128];
  __shared__ __align__(16) float4 yh_l[64];

  const int g = blockIdx.x, tid = threadIdx.x;
  const int b = g & 127, p = g >> 7, other = g ^ 128;
  const int l = tid & 63, wv = tid >> 6;

  // ---- register-resident weights ----
  const int e_own = 128 * p + (tid >> 1), kh = tid & 1;
  uint4 w1r[32];  // k-half (256 f16) of w1 row e_own over [h|c]
  {
    const float4* s = (const float4*)(w1 + (size_t)e_own * 768 + kh * 256);
#pragma unroll
    for (int i = 0; i < 32; i++) {
      float4 x = s[2 * i], y = s[2 * i + 1];
      w1r[i].x = pk(x.x, x.y); w1r[i].y = pk(x.z, x.w);
      w1r[i].z = pk(y.x, y.y); w1r[i].w = pk(y.z, y.w);
    }
  }
  const int q2 = tid >> 7, dl = tid & 127, d_own = 128 * p + dl;
  const int ra = q2 * 256 + d_own, rb = (q2 + 2) * 256 + d_own;  // (i,g) or (f,o)
  uint4 wA[32], wB[32];  // full 256-f16 w_hh rows
  {
    const float4* s = (const float4*)(w_hh + (size_t)ra * 256);
#pragma unroll
    for (int i = 0; i < 32; i++) {
      float4 x = s[2 * i], y = s[2 * i + 1];
      wA[i].x = pk(x.x, x.y); wA[i].y = pk(x.z, x.w);
      wA[i].z = pk(y.x, y.y); wA[i].w = pk(y.z, y.w);
    }
    const float4* s2 = (const float4*)(w_hh + (size_t)rb * 256);
#pragma unroll
    for (int i = 0; i < 32; i++) {
      float4 x = s2[2 * i], y = s2[2 * i + 1];
      wB[i].x = pk(x.x, x.y); wB[i].y = pk(x.z, x.w);
      wB[i].z = pk(y.x, y.y); wB[i].w = pk(y.z, y.w);
    }
  }
  const float4 wihA = *(const float4*)(w_ih + (size_t)ra * 4);
  const float4 wihB = *(const float4*)(w_ih + (size_t)rb * 4);
  const float bsA = b_ih[ra] + b_hh[ra];
  const float bsB = b_ih[rb] + b_hh[rb];

  // ---- LDS init ----
  if (tid < 128) { w2_l[tid] = w2[128 * p + tid]; c32_l[tid] = 0.f; hn_l[tid] = 0.f; }
  st_l[tid] = 0u;
  if (tid < 64) {
    yh_l[tid] = ((const float4*)yhist)[b * 64 + tid];
    encfc_l[tid] = g_encfc[b * 64 + tid];
    encfcf_l[tid] = g_encfcf[b * 64 + tid];
  }
  if (tid < 16) fcy_l[tid] = fc_w[(tid >> 2) * 260 + 256 + (tid & 3)];
  if (tid < 4) fcb_l[tid] = fc_b[tid];
#pragma unroll
  for (int i = 0; i < 4; i++) {
    int lin = i * 256 + tid;          // 1024 uint4 tasks
    int w = lin >> 4, u = lin & 15;
    uint4 v = ((const uint4*)(g_ep16 + ((size_t)(b * 64 + w)) * 128 + 64 * p))[u];
    *(uint4*)&ep16[w * 68 + u * 4] = v;
  }
  __syncthreads();

  float attw = 0.f;
  for (int t = 0; t < Wn; t++) {
    const unsigned want = (unsigned)(t + 1);
    // ---- P1: hcp[e_own], k-half per thread ----
    {
      float a = 0.f;
      const uint4* hv = (const uint4*)&st_l[kh * 128];
#pragma unroll
      for (int i = 0; i < 32; i++) a = fd2x4u(w1r[i], hv[i], a);
      a += __shfl_xor(a, 1, 64);
      if (kh == 0) hcp_l[e_own] = a;
    }
    __syncthreads();  // B1
    // ---- P2: partial scores over own e-half ----
    {
      const int w = tid >> 2, j = tid & 3;
      const unsigned* ep = &ep16[w * 68 + j * 16];
      const float* hp = &hcp_l[128 * p + j * 32];
      const float* vv = &w2_l[j * 32];
      float s = 0.f;
#pragma unroll
      for (int i = 0; i < 4; i++) {
        uint4 u = *(const uint4*)(ep + 4 * i);
        float4 h0 = *(const float4*)(hp + 8 * i);
        float4 h1 = *(const float4*)(hp + 8 * i + 4);
        float4 v0 = *(const float4*)(vv + 8 * i);
        float4 v1 = *(const float4*)(vv + 8 * i + 4);
        h2 aa;
        aa = __builtin_bit_cast(h2, u.x);
        s += v0.x * ftanh((float)aa.x + h0.x) + v0.y * ftanh((float)aa.y + h0.y);
        aa = __builtin_bit_cast(h2, u.y);
        s += v0.z * ftanh((float)aa.x + h0.z) + v0.w * ftanh((float)aa.y + h0.w);
        aa = __builtin_bit_cast(h2, u.z);
        s += v1.x * ftanh((float)aa.x + h1.x) + v1.y * ftanh((float)aa.y + h1.y);
        aa = __builtin_bit_cast(h2, u.w);
        s += v1.z * ftanh((float)aa.x + h1.z) + v1.w * ftanh((float)aa.y + h1.w);
      }
      s += __shfl_xor(s, 1, 64);
      s += __shfl_xor(s, 2, 64);
      if (j == 0) { att_l[w] = s; ast(&g_att[g][w], __builtin_bit_cast(unsigned, s)); }
    }
    __syncthreads();  // B2 (drains each wave's stores)
    if (tid == 0) ast_rel(&g_f1[g], want);
    // ---- exchange + softmax + ytilde (per-wave redundant, no barrier) ----
    float sc;
    {
      while (ald_acq(&g_f1[other]) < want) __builtin_amdgcn_s_sleep(1);
      sc = att_l[l] + __builtin_bit_cast(float, ald(&g_att[other][l]));
    }
    float m = sc;
#pragma unroll
    for (int dd = 32; dd; dd >>= 1) m = fmaxf(m, __shfl_xor(m, dd, 64));
    float pr = __builtin_exp2f((sc - m) * 1.4426950408889634f);
    float su = pr;
#pragma unroll
    for (int dd = 32; dd; dd >>= 1) su += __shfl_xor(su, dd, 64);
    attw = pr * __builtin_amdgcn_rcpf(su);
    float4 yt4;
    {
      float4 ef = encfc_l[l];
      float rx = attw * ef.x, ry = attw * ef.y, rz = attw * ef.z, rw = attw * ef.w;
#pragma unroll
      for (int dd = 32; dd; dd >>= 1) {
        rx += __shfl_xor(rx, dd, 64);
        ry += __shfl_xor(ry, dd, 64);
        rz += __shfl_xor(rz, dd, 64);
        rw += __shfl_xor(rw, dd, 64);
      }
      float4 yv = yh_l[t];
      yt4.x = rx + fcb_l[0] + fcy_l[0] * yv.x + fcy_l[1] * yv.y + fcy_l[2] * yv.z + fcy_l[3] * yv.w;
      yt4.y = ry + fcb_l[1] + fcy_l[4] * yv.x + fcy_l[5] * yv.y + fcy_l[6] * yv.z + fcy_l[7] * yv.w;
      yt4.z = rz + fcb_l[2] + fcy_l[8] * yv.x + fcy_l[9] * yv.y + fcy_l[10] * yv.z + fcy_l[11] * yv.w;
      yt4.w = rw + fcb_l[3] + fcy_l[12] * yv.x + fcy_l[13] * yv.y + fcy_l[14] * yv.z + fcy_l[15] * yv.w;
    }
    // ---- P6: gates (2 rows/thread, register weights, broadcast h) ----
    {
      float aA = bsA + dot4(wihA, yt4);
      float aB = bsB + dot4(wihB, yt4);
      const uint4* hv = (const uint4*)st_l;  // h pairs
#pragma unroll
      for (int i = 0; i < 32; i++) {
        uint4 hh = hv[i];
        aA = fd2x4u(wA[i], hh, aA);
        aB = fd2x4u(wB[i], hh, aB);
      }
      if (q2 == 0) { ai_l[dl] = aA; ag_l[dl] = aB; }
      else         { af_l[dl] = aA; ao_l[dl] = aB; }
    }
    __syncthreads();  // B3
    if (tid < 128) {
      float ig = fsigm(ai_l[tid]), fg = fsigm(af_l[tid]);
      float gg = ftanh(ag_l[tid]), og = fsigm(ao_l[tid]);
      float cn = fg * c32_l[tid] + ig * gg;
      float hn = og * ftanh(cn);
      c32_l[tid] = cn;
      hn_l[tid] = hn;
    }
    __syncthreads();  // B4
    if (t < 63) {
      if (tid < 64) {
        unsigned hp = pk(hn_l[2 * tid], hn_l[2 * tid + 1]);
        unsigned cp = pk(c32_l[2 * tid], c32_l[2 * tid + 1]);
        st_l[64 * p + tid] = hp;
        st_l[128 + 64 * p + tid] = cp;
        ast(&g_state[g][tid], hp);
        ast(&g_state[g][64 + tid], cp);
        if (tid == 0) ast_rel(&g_f2[g], want);  // release waits wave0's stores
      } else if (tid < 128) {
        const int i = tid - 64;
        while (ald_acq(&g_f2[other]) < want) __builtin_amdgcn_s_sleep(1);
        st_l[64 * (1 - p) + i] = ald(&g_state[other][i]);
        st_l[128 + 64 * (1 - p) + i] = ald(&g_state[other][64 + i]);
      }
    }
    __syncthreads();  // B5
  }

  // ---- final: out[b,f] = fcf_h·h + attn·ENCFCF + fcf_b (atomicAdd, 2 contributions) ----
  {
    const int f = wv;
    float v = fcf_w[f * 512 + 128 * p + l] * hn_l[l] +
              fcf_w[f * 512 + 128 * p + 64 + l] * hn_l[64 + l];
    if (p == 0) v += attw * ((const float*)&encfcf_l[l])[f];
#pragma unroll
    for (int dd = 32; dd; dd >>= 1) v += __shfl_xor(v, dd, 64);
    if (l == 0) atomicAdd(out + b * 4 + f, v + (p == 0 ? fcf_b[f] : 0.f));
  }
}

extern "C" void kernel_launch(void* const* d_in, const int* in_sizes, int n_in,
                              void* d_out, int out_size, void* d_ws, size_t ws_size,
                              hipStream_t stream) {
  (void)in_sizes; (void)n_in; (void)d_ws; (void)ws_size; (void)out_size;
  const float* enc   = (const float*)d_in[0];
  const float* yhist = (const float*)d_in[1];
  const float* w1    = (const float*)d_in[2];
  const float* b1    = (const float*)d_in[3];
  const float* w2    = (const float*)d_in[4];
  // d_in[5] = attn_b2: softmax-invariant -> unused
  const float* w_ih  = (const float*)d_in[6];
  const float* w_hh  = (const float*)d_in[7];
  const float* b_ih  = (const float*)d_in[8];
  const float* b_hh  = (const float*)d_in[9];
  const float* fc_w  = (const float*)d_in[10];
  const float* fc_b  = (const float*)d_in[11];
  const float* fcf_w = (const float*)d_in[12];
  const float* fcf_b = (const float*)d_in[13];
  float* out = (float*)d_out;

  reset_kernel<<<dim3(1), dim3(512), 0, stream>>>(out);
  eproj_kernel<<<dim3(512), dim3(256), 0, stream>>>(enc, w1, b1);
  encfc_kernel<<<dim3(512), dim3(256), 0, stream>>>(enc, fc_w, fcf_w);
  decoder_kernel<<<dim3(256), dim3(256), 0, stream>>>(w1, w_hh, yhist, w2, w_ih, b_ih,
                                                      b_hh, fc_w, fc_b, fcf_w, fcf_b, out);
}